// Round 16
// baseline (97.466 us; speedup 1.0000x reference)
//
#include <hip/hip_runtime.h>

#define NEG 0.2f
#define BN   128        // nodes per bucket
#define CAP  2560       // bucket capacity; mean 2048, +11 sigma
#define ED   10         // edges per thread (ED*256 == CAP)
#define EPB  2048       // edges per scatter block

__device__ __forceinline__ float leaky(float v){ return fmaxf(v, NEG * v); }

// order-preserving float<->uint map for atomicMax on floats
__device__ __forceinline__ unsigned fmap(float f){
    unsigned b = __float_as_uint(f);
    return (b & 0x80000000u) ? ~b : (b | 0x80000000u);
}
__device__ __forceinline__ float funmap(unsigned u){
    return (u & 0x80000000u) ? __uint_as_float(u & 0x7fffffffu) : __uint_as_float(~u);
}

// seed per-bucket global cursors at b*CAP
__global__ void __launch_bounds__(256) k_init(int* __restrict__ gcur, int nb){
    int t = blockIdx.x * 256 + threadIdx.x;
    if (t < nb) gcur[t] = t * CAP;
}

// ---------------------------------------------------------------------------
// k_scatter: per block of 2048 edges, LDS histogram of bucket = dst>>7, ONE
// global atomicAdd per (block,bucket) to reserve a contiguous run (~5 edges),
// then scatter 16B records {xs, xd, a, dst&127} into the run -> ~2.5x fewer
// scattered sectors than per-edge stores.
// ---------------------------------------------------------------------------
__global__ void __launch_bounds__(256) k_scatter(
        const int* __restrict__ src, const int* __restrict__ dst,
        const float* __restrict__ attr, const float* __restrict__ x,
        int* __restrict__ gcur, float4* __restrict__ sorted, int E, int nb){
    __shared__ int hist[512];
    __shared__ int cur[512];
    const int tid = threadIdx.x;
    for (int k = tid; k < nb; k += 256) hist[k] = 0;
    __syncthreads();
    const int base = blockIdx.x * EPB;
    const int lim  = min(EPB, E - base);
    for (int k = tid; k < lim; k += 256)
        atomicAdd(&hist[dst[base + k] >> 7], 1);       // LDS
    __syncthreads();
    for (int k = tid; k < nb; k += 256){
        int c = hist[k];
        cur[k] = c ? atomicAdd(&gcur[k], c) : 0;       // global, aggregated
    }
    __syncthreads();
    for (int k = tid; k < lim; k += 256){
        int e = base + k;
        int d = dst[e];
        int b = d >> 7;
        int pos = atomicAdd(&cur[b], 1);               // LDS; global slot (seeded)
        if (pos < (b + 1) * CAP)
            sorted[pos] = make_float4(x[src[e]], x[d], attr[e],
                                      __int_as_float(d & (BN - 1)));
    }
}

// ---------------------------------------------------------------------------
// k_node: one 256-thread block per 128-node bucket. Each thread holds ED=10
// edges IN REGISTERS; channel loop walks 4-channel chunks (5 LDS reads)
// reused across all 10 edges -> ~16 LDS inst/edge. __launch_bounds__(256,4)
// grants a 128-VGPR budget so the blocking survives regalloc (r15's 40-VGPR
// occupancy-greedy default destroyed it). Exact per-node max via LDS
// atomicMax; accumulate via LDS atomicAdd; 16-lane epilogue per node.
// ---------------------------------------------------------------------------
__global__ void __launch_bounds__(256, 4) k_node(
        const float* __restrict__ x,
        const int* __restrict__ gcur, const float4* __restrict__ sorted,
        const float* __restrict__ Wl, const float* __restrict__ Wr,
        const float* __restrict__ We, const float* __restrict__ bl,
        const float* __restrict__ br, const float* __restrict__ att,
        const float* __restrict__ bias,
        float4* __restrict__ out, int N){
    __shared__ float4   pk[128];        // {Wl, Wr, We, bl+br}
    __shared__ float4   pat4[32];       // att as float4
    __shared__ float    pat[128];       // att scalar (epilogue)
    __shared__ unsigned mm[BN][2];
    __shared__ float    dd[BN][2];
    __shared__ float    nn[BN][2];
    __shared__ float    as_[BN];
    __shared__ int      dg[BN];
    const int tid = threadIdx.x;
    const int b   = blockIdx.x;
    if (tid < 128){
        pk[tid]  = make_float4(Wl[tid], Wr[tid], We[tid], bl[tid] + br[tid]);
        pat[tid] = att[tid];
        mm[tid][0] = 0u;  mm[tid][1] = 0u;
        dd[tid][0] = 0.f; dd[tid][1] = 0.f;
        nn[tid][0] = 0.f; nn[tid][1] = 0.f;
        as_[tid] = 0.f;   dg[tid] = 0;
    }
    if (tid < 32) pat4[tid] = ((const float4*)att)[tid];
    __syncthreads();

    int cnt = gcur[b] - b * CAP;
    if (cnt > CAP) cnt = CAP;
    const float4* bucket = sorted + (size_t)b * CAP;

    // ---- load ED edges into registers (coalesced, stride 256) ----
    float xs[ED], xd[ED], aa[ED], l0[ED], l1[ED];
    int   nd[ED];
    #pragma unroll
    for (int k = 0; k < ED; ++k){
        int idx = k * 256 + tid;
        if (idx < cnt){
            float4 f = bucket[idx];
            xs[k] = f.x; xd[k] = f.y; aa[k] = f.z;
            nd[k] = __float_as_int(f.w) & (BN - 1);
        } else {
            xs[k] = 0.f; xd[k] = 0.f; aa[k] = 0.f; nd[k] = -1;
        }
        l0[k] = 0.f; l1[k] = 0.f;
    }

    // ---- phase A: 4-channel chunks, weights reused across ED edges ----
    #pragma unroll 2
    for (int c = 0; c < 16; ++c){           // head 0: channels 0..63
        float4 p0 = pk[4*c], p1 = pk[4*c+1], p2 = pk[4*c+2], p3 = pk[4*c+3];
        float4 at = pat4[c];
        #pragma unroll
        for (int k = 0; k < ED; ++k){
            float v;
            v = fmaf(xs[k], p0.x, fmaf(xd[k], p0.y, fmaf(aa[k], p0.z, p0.w)));
            l0[k] = fmaf(leaky(v), at.x, l0[k]);
            v = fmaf(xs[k], p1.x, fmaf(xd[k], p1.y, fmaf(aa[k], p1.z, p1.w)));
            l0[k] = fmaf(leaky(v), at.y, l0[k]);
            v = fmaf(xs[k], p2.x, fmaf(xd[k], p2.y, fmaf(aa[k], p2.z, p2.w)));
            l0[k] = fmaf(leaky(v), at.z, l0[k]);
            v = fmaf(xs[k], p3.x, fmaf(xd[k], p3.y, fmaf(aa[k], p3.z, p3.w)));
            l0[k] = fmaf(leaky(v), at.w, l0[k]);
        }
    }
    #pragma unroll 2
    for (int c = 16; c < 32; ++c){          // head 1: channels 64..127
        float4 p0 = pk[4*c], p1 = pk[4*c+1], p2 = pk[4*c+2], p3 = pk[4*c+3];
        float4 at = pat4[c];
        #pragma unroll
        for (int k = 0; k < ED; ++k){
            float v;
            v = fmaf(xs[k], p0.x, fmaf(xd[k], p0.y, fmaf(aa[k], p0.z, p0.w)));
            l1[k] = fmaf(leaky(v), at.x, l1[k]);
            v = fmaf(xs[k], p1.x, fmaf(xd[k], p1.y, fmaf(aa[k], p1.z, p1.w)));
            l1[k] = fmaf(leaky(v), at.y, l1[k]);
            v = fmaf(xs[k], p2.x, fmaf(xd[k], p2.y, fmaf(aa[k], p2.z, p2.w)));
            l1[k] = fmaf(leaky(v), at.z, l1[k]);
            v = fmaf(xs[k], p3.x, fmaf(xd[k], p3.y, fmaf(aa[k], p3.z, p3.w)));
            l1[k] = fmaf(leaky(v), at.w, l1[k]);
        }
    }
    #pragma unroll
    for (int k = 0; k < ED; ++k){
        if (nd[k] >= 0){
            atomicMax(&mm[nd[k]][0], fmap(l0[k]));
            atomicMax(&mm[nd[k]][1], fmap(l1[k]));
        }
    }
    __syncthreads();

    // ---- phase B: exp + LDS accumulate (logits still in registers) ----
    #pragma unroll
    for (int k = 0; k < ED; ++k){
        if (nd[k] >= 0){
            float p0 = __expf(l0[k] - funmap(mm[nd[k]][0]));
            float p1 = __expf(l1[k] - funmap(mm[nd[k]][1]));
            atomicAdd(&dd[nd[k]][0], p0);
            atomicAdd(&nn[nd[k]][0], p0 * xs[k]);
            atomicAdd(&dd[nd[k]][1], p1);
            atomicAdd(&nn[nd[k]][1], p1 * xs[k]);
            atomicAdd(&as_[nd[k]], aa[k]);
            atomicAdd(&dg[nd[k]], 1);
        }
    }
    __syncthreads();

    // ---- epilogue: 8 passes x 16 nodes; 16 lanes per node ----
    const int ln  = tid & 15;
    const int grp = tid >> 4;           // 0..15
    const float4* Wl4 = (const float4*)Wl;
    const float4* bl4 = (const float4*)bl;
    const float4* bs4 = (const float4*)bias;
    float4 ww0 = Wl4[ln],  ww1 = Wl4[ln + 16];
    float4 gg0 = bl4[ln],  gg1 = bl4[ln + 16];
    float4 z0  = bs4[ln],  z1  = bs4[ln + 16];
    #pragma unroll
    for (int r = 0; r < 8; ++r){
        int node = r * 16 + grp;
        int i = b * BN + node;
        if (i >= N) continue;
        int   degv = dg[node];
        float m0 = degv ? funmap(mm[node][0]) : -3.4e38f;
        float m1 = degv ? funmap(mm[node][1]) : -3.4e38f;
        float d0 = dd[node][0], n0 = nn[node][0];
        float d1 = dd[node][1], n1 = nn[node][1];
        float la = as_[node] / (float)max(degv, 1);
        float xi = x[i];
        // self-loop logit: lane ln owns channels k*16+ln
        float pl0 = 0.f, pl1 = 0.f;
        #pragma unroll
        for (int k = 0; k < 4; ++k){
            int c = k * 16 + ln;
            float4 p = pk[c];
            float v = fmaf(xi, p.x + p.y, fmaf(la, p.z, p.w));
            pl0 = fmaf(leaky(v), pat[c], pl0);
        }
        #pragma unroll
        for (int k = 4; k < 8; ++k){
            int c = k * 16 + ln;
            float4 p = pk[c];
            float v = fmaf(xi, p.x + p.y, fmaf(la, p.z, p.w));
            pl1 = fmaf(leaky(v), pat[c], pl1);
        }
        pl0 += __shfl_xor(pl0, 1); pl1 += __shfl_xor(pl1, 1);
        pl0 += __shfl_xor(pl0, 2); pl1 += __shfl_xor(pl1, 2);
        pl0 += __shfl_xor(pl0, 4); pl1 += __shfl_xor(pl1, 4);
        pl0 += __shfl_xor(pl0, 8); pl1 += __shfl_xor(pl1, 8);
        // fold self-loop into reduced softmax state
        {
            float mn = fmaxf(m0, pl0);
            float s = __expf(m0 - mn), p = __expf(pl0 - mn);
            d0 = fmaf(d0, s, p);
            n0 = fmaf(n0, s, p * xi);
        }
        {
            float mn = fmaxf(m1, pl1);
            float s = __expf(m1 - mn), p = __expf(pl1 - mn);
            d1 = fmaf(d1, s, p);
            n1 = fmaf(n1, s, p * xi);
        }
        float sres0 = n0 / d0;
        float sres1 = n1 / d1;
        float4* orow = out + (size_t)i * 32;
        orow[ln]      = make_float4(fmaf(sres0, ww0.x, gg0.x + z0.x),
                                    fmaf(sres0, ww0.y, gg0.y + z0.y),
                                    fmaf(sres0, ww0.z, gg0.z + z0.z),
                                    fmaf(sres0, ww0.w, gg0.w + z0.w));
        orow[ln + 16] = make_float4(fmaf(sres1, ww1.x, gg1.x + z1.x),
                                    fmaf(sres1, ww1.y, gg1.y + z1.y),
                                    fmaf(sres1, ww1.z, gg1.z + z1.z),
                                    fmaf(sres1, ww1.w, gg1.w + z1.w));
    }
}

extern "C" void kernel_launch(void* const* d_in, const int* in_sizes, int n_in,
                              void* d_out, int out_size, void* d_ws, size_t ws_size,
                              hipStream_t stream) {
    const float* x    = (const float*)d_in[0];
    const int*   ei   = (const int*)  d_in[1];
    const float* attr = (const float*)d_in[2];
    const float* Wl   = (const float*)d_in[3];
    const float* bl   = (const float*)d_in[4];
    const float* Wr   = (const float*)d_in[5];
    const float* br   = (const float*)d_in[6];
    const float* We   = (const float*)d_in[7];
    const float* att  = (const float*)d_in[8];
    const float* bias = (const float*)d_in[9];
    float* out = (float*)d_out;

    const int N = in_sizes[0];       // 50000
    const int E = in_sizes[2];       // 800000
    const int* src = ei;
    const int* dst = ei + E;

    const int nb = (N + BN - 1) / BN;   // 391 buckets of 128 nodes

    // workspace: sorted [nb*CAP]float4 (~16 MB) | gcur [nb]int
    char* w = (char*)d_ws;
    float4* sorted = (float4*)w;
    int*    gcur   = (int*)(w + (size_t)nb * CAP * 16);

    k_init<<<(nb + 255) / 256, 256, 0, stream>>>(gcur, nb);
    k_scatter<<<(E + EPB - 1) / EPB, 256, 0, stream>>>(src, dst, attr, x,
                                                       gcur, sorted, E, nb);
    k_node<<<nb, 256, 0, stream>>>(x, gcur, sorted,
                                   Wl, Wr, We, bl, br, att, bias,
                                   (float4*)out, N);
}

// Round 17
// 89.184 us; speedup vs baseline: 1.0929x; 1.0929x over previous
//
#include <hip/hip_runtime.h>

#define NEG 0.2f
#define BN   128        // nodes per bucket
#define CAP  2560       // bucket capacity; mean 2048, +11 sigma
#define EPB  2048       // edges per scatter block

__device__ __forceinline__ float leaky(float v){ return fmaxf(v, NEG * v); }

// order-preserving float<->uint map for atomicMax on floats
__device__ __forceinline__ unsigned fmap(float f){
    unsigned b = __float_as_uint(f);
    return (b & 0x80000000u) ? ~b : (b | 0x80000000u);
}
__device__ __forceinline__ float funmap(unsigned u){
    return (u & 0x80000000u) ? __uint_as_float(u & 0x7fffffffu) : __uint_as_float(~u);
}

// seed per-bucket global cursors at b*CAP
__global__ void __launch_bounds__(256) k_init(int* __restrict__ gcur, int nb){
    int t = blockIdx.x * 256 + threadIdx.x;
    if (t < nb) gcur[t] = t * CAP;
}

// ---------------------------------------------------------------------------
// k_scatter: per block of 2048 edges, LDS histogram of bucket = dst>>7, ONE
// global atomicAdd per (block,bucket) to reserve a contiguous run (~5 edges),
// then scatter 16B records {x[src], attr, node, 0}. x[dst] is NOT gathered
// here (r16's hidden ~halving of scatter cost) — k_node reads it from an LDS
// xnode table instead.
// ---------------------------------------------------------------------------
__global__ void __launch_bounds__(256) k_scatter(
        const int* __restrict__ src, const int* __restrict__ dst,
        const float* __restrict__ attr, const float* __restrict__ x,
        int* __restrict__ gcur, float4* __restrict__ sorted, int E, int nb){
    __shared__ int hist[512];
    __shared__ int cur[512];
    const int tid = threadIdx.x;
    for (int k = tid; k < nb; k += 256) hist[k] = 0;
    __syncthreads();
    const int base = blockIdx.x * EPB;
    const int lim  = min(EPB, E - base);
    for (int k = tid; k < lim; k += 256)
        atomicAdd(&hist[dst[base + k] >> 7], 1);       // LDS
    __syncthreads();
    for (int k = tid; k < nb; k += 256){
        int c = hist[k];
        cur[k] = c ? atomicAdd(&gcur[k], c) : 0;       // global, aggregated
    }
    __syncthreads();
    for (int k = tid; k < lim; k += 256){
        int e = base + k;
        int d = dst[e];
        int b = d >> 7;
        int pos = atomicAdd(&cur[b], 1);               // LDS; global slot (seeded)
        if (pos < (b + 1) * CAP)
            sorted[pos] = make_float4(x[src[e]], attr[e],
                                      (float)(d & (BN - 1)), 0.f);
    }
}

// per-channel logit step macro: v = xs*Wl + xd*Wr + a*We + bsum; acc += leaky(v)*att
#define CH(P, AT, X, D, T, ACC) { \
    float v_ = fmaf((X), (P).x, fmaf((D), (P).y, fmaf((T), (P).z, (P).w))); \
    (ACC) = fmaf(leaky(v_), (AT), (ACC)); }

// all 5 edges, one channel
#define CH5(P, AT) \
    CH(P, AT, X0, D0, T0, ACur0) CH(P, AT, X1, D1, T1, ACur1) \
    CH(P, AT, X2, D2, T2, ACur2) CH(P, AT, X3, D3, T3, ACur3) \
    CH(P, AT, X4, D4, T4, ACur4)

// ---------------------------------------------------------------------------
// k_node: one 512-thread block per 128-node bucket. Each thread holds 5 edges
// as EXPLICIT NAMED SCALARS (no arrays -> nothing to demote); the channel
// loop walks 4-channel chunks (5 LDS reads) reused across the 5 edges
// (~32 LDS inst/edge). asm "+v" barrier pins the accumulators in VGPRs.
// xd comes from the LDS xnode table (same for all edges of a node).
// ---------------------------------------------------------------------------
__global__ void __launch_bounds__(512, 2) k_node(
        const float* __restrict__ x,
        const int* __restrict__ gcur, const float4* __restrict__ sorted,
        const float* __restrict__ Wl, const float* __restrict__ Wr,
        const float* __restrict__ We, const float* __restrict__ bl,
        const float* __restrict__ br, const float* __restrict__ att,
        const float* __restrict__ bias,
        float4* __restrict__ out, int N){
    __shared__ float4   pk[128];        // {Wl, Wr, We, bl+br}
    __shared__ float4   pat4[32];       // att as float4
    __shared__ float    pat[128];       // att scalar (epilogue)
    __shared__ float    xnode[BN];      // x of this bucket's nodes
    __shared__ unsigned mm[BN][2];
    __shared__ float    dd[BN][2];
    __shared__ float    nn[BN][2];
    __shared__ float    as_[BN];
    __shared__ int      dg[BN];
    const int tid = threadIdx.x;
    const int b   = blockIdx.x;
    if (tid < 128){
        pk[tid]  = make_float4(Wl[tid], Wr[tid], We[tid], bl[tid] + br[tid]);
        pat[tid] = att[tid];
        int i = b * BN + tid;
        xnode[tid] = (i < N) ? x[i] : 0.f;
        mm[tid][0] = 0u;  mm[tid][1] = 0u;
        dd[tid][0] = 0.f; dd[tid][1] = 0.f;
        nn[tid][0] = 0.f; nn[tid][1] = 0.f;
        as_[tid] = 0.f;   dg[tid] = 0;
    }
    if (tid < 32) pat4[tid] = ((const float4*)att)[tid];
    __syncthreads();

    int cnt = gcur[b] - b * CAP;
    if (cnt > CAP) cnt = CAP;
    const float4* bucket = sorted + (size_t)b * CAP;

    // ---- load 5 edges as named scalars (coalesced, stride 512) ----
    float X0=0.f,X1=0.f,X2=0.f,X3=0.f,X4=0.f;      // xs
    float T0=0.f,T1=0.f,T2=0.f,T3=0.f,T4=0.f;      // attr
    float D0=0.f,D1=0.f,D2=0.f,D3=0.f,D4=0.f;      // xd (from xnode)
    int   n0=-1,n1=-1,n2=-1,n3=-1,n4=-1;
    {
        int i0 = tid, i1 = tid+512, i2 = tid+1024, i3 = tid+1536, i4 = tid+2048;
        if (i0 < cnt){ float4 f = bucket[i0]; X0=f.x; T0=f.y; n0=(int)f.z; D0=xnode[n0]; }
        if (i1 < cnt){ float4 f = bucket[i1]; X1=f.x; T1=f.y; n1=(int)f.z; D1=xnode[n1]; }
        if (i2 < cnt){ float4 f = bucket[i2]; X2=f.x; T2=f.y; n2=(int)f.z; D2=xnode[n2]; }
        if (i3 < cnt){ float4 f = bucket[i3]; X3=f.x; T3=f.y; n3=(int)f.z; D3=xnode[n3]; }
        if (i4 < cnt){ float4 f = bucket[i4]; X4=f.x; T4=f.y; n4=(int)f.z; D4=xnode[n4]; }
    }

    // ---- phase A: 4-channel chunks, weights reused across the 5 edges ----
    float A0=0.f,A1=0.f,A2=0.f,A3=0.f,A4=0.f;      // head-0 logits
    float B0=0.f,B1=0.f,B2=0.f,B3=0.f,B4=0.f;      // head-1 logits
    #pragma unroll 2
    for (int c = 0; c < 16; ++c){                  // head 0: channels 0..63
        float4 p0 = pk[4*c], p1 = pk[4*c+1], p2 = pk[4*c+2], p3 = pk[4*c+3];
        float4 at = pat4[c];
        #define ACur0 A0
        #define ACur1 A1
        #define ACur2 A2
        #define ACur3 A3
        #define ACur4 A4
        CH5(p0, at.x) CH5(p1, at.y) CH5(p2, at.z) CH5(p3, at.w)
        #undef ACur0
        #undef ACur1
        #undef ACur2
        #undef ACur3
        #undef ACur4
    }
    #pragma unroll 2
    for (int c = 16; c < 32; ++c){                 // head 1: channels 64..127
        float4 p0 = pk[4*c], p1 = pk[4*c+1], p2 = pk[4*c+2], p3 = pk[4*c+3];
        float4 at = pat4[c];
        #define ACur0 B0
        #define ACur1 B1
        #define ACur2 B2
        #define ACur3 B3
        #define ACur4 B4
        CH5(p0, at.x) CH5(p1, at.y) CH5(p2, at.z) CH5(p3, at.w)
        #undef ACur0
        #undef ACur1
        #undef ACur2
        #undef ACur3
        #undef ACur4
    }
    // pin accumulators in VGPRs (defeat recompute/demotion)
    asm volatile("" : "+v"(A0), "+v"(A1), "+v"(A2), "+v"(A3), "+v"(A4),
                      "+v"(B0), "+v"(B1), "+v"(B2), "+v"(B3), "+v"(B4));

    if (n0 >= 0){ atomicMax(&mm[n0][0], fmap(A0)); atomicMax(&mm[n0][1], fmap(B0)); }
    if (n1 >= 0){ atomicMax(&mm[n1][0], fmap(A1)); atomicMax(&mm[n1][1], fmap(B1)); }
    if (n2 >= 0){ atomicMax(&mm[n2][0], fmap(A2)); atomicMax(&mm[n2][1], fmap(B2)); }
    if (n3 >= 0){ atomicMax(&mm[n3][0], fmap(A3)); atomicMax(&mm[n3][1], fmap(B3)); }
    if (n4 >= 0){ atomicMax(&mm[n4][0], fmap(A4)); atomicMax(&mm[n4][1], fmap(B4)); }
    __syncthreads();

    // ---- phase B: exp + LDS accumulate (logits still in registers) ----
    #define PHB(NN, AA, BB, XX, TT) \
    if (NN >= 0){ \
        float p0_ = __expf(AA - funmap(mm[NN][0])); \
        float p1_ = __expf(BB - funmap(mm[NN][1])); \
        atomicAdd(&dd[NN][0], p0_); \
        atomicAdd(&nn[NN][0], p0_ * XX); \
        atomicAdd(&dd[NN][1], p1_); \
        atomicAdd(&nn[NN][1], p1_ * XX); \
        atomicAdd(&as_[NN], TT); \
        atomicAdd(&dg[NN], 1); }
    PHB(n0, A0, B0, X0, T0)
    PHB(n1, A1, B1, X1, T1)
    PHB(n2, A2, B2, X2, T2)
    PHB(n3, A3, B3, X3, T3)
    PHB(n4, A4, B4, X4, T4)
    #undef PHB
    __syncthreads();

    // ---- epilogue: 4 passes x 32 nodes; 16 lanes per node ----
    const int ln  = tid & 15;
    const int grp = tid >> 4;           // 0..31
    const float4* Wl4 = (const float4*)Wl;
    const float4* bl4 = (const float4*)bl;
    const float4* bs4 = (const float4*)bias;
    float4 ww0 = Wl4[ln],  ww1 = Wl4[ln + 16];
    float4 gg0 = bl4[ln],  gg1 = bl4[ln + 16];
    float4 z0  = bs4[ln],  z1  = bs4[ln + 16];
    #pragma unroll
    for (int r = 0; r < 4; ++r){
        int node = r * 32 + grp;
        int i = b * BN + node;
        if (i >= N) continue;
        int   degv = dg[node];
        float m0 = degv ? funmap(mm[node][0]) : -3.4e38f;
        float m1 = degv ? funmap(mm[node][1]) : -3.4e38f;
        float d0 = dd[node][0], n0v = nn[node][0];
        float d1 = dd[node][1], n1v = nn[node][1];
        float la = as_[node] / (float)max(degv, 1);
        float xi = xnode[node];
        // self-loop logit: lane ln owns channels k*16+ln
        float pl0 = 0.f, pl1 = 0.f;
        #pragma unroll
        for (int k = 0; k < 4; ++k){
            int c = k * 16 + ln;
            float4 p = pk[c];
            float v = fmaf(xi, p.x + p.y, fmaf(la, p.z, p.w));
            pl0 = fmaf(leaky(v), pat[c], pl0);
        }
        #pragma unroll
        for (int k = 4; k < 8; ++k){
            int c = k * 16 + ln;
            float4 p = pk[c];
            float v = fmaf(xi, p.x + p.y, fmaf(la, p.z, p.w));
            pl1 = fmaf(leaky(v), pat[c], pl1);
        }
        pl0 += __shfl_xor(pl0, 1); pl1 += __shfl_xor(pl1, 1);
        pl0 += __shfl_xor(pl0, 2); pl1 += __shfl_xor(pl1, 2);
        pl0 += __shfl_xor(pl0, 4); pl1 += __shfl_xor(pl1, 4);
        pl0 += __shfl_xor(pl0, 8); pl1 += __shfl_xor(pl1, 8);
        // fold self-loop into reduced softmax state
        {
            float mn = fmaxf(m0, pl0);
            float s = __expf(m0 - mn), p = __expf(pl0 - mn);
            d0 = fmaf(d0, s, p);
            n0v = fmaf(n0v, s, p * xi);
        }
        {
            float mn = fmaxf(m1, pl1);
            float s = __expf(m1 - mn), p = __expf(pl1 - mn);
            d1 = fmaf(d1, s, p);
            n1v = fmaf(n1v, s, p * xi);
        }
        float sres0 = n0v / d0;
        float sres1 = n1v / d1;
        float4* orow = out + (size_t)i * 32;
        orow[ln]      = make_float4(fmaf(sres0, ww0.x, gg0.x + z0.x),
                                    fmaf(sres0, ww0.y, gg0.y + z0.y),
                                    fmaf(sres0, ww0.z, gg0.z + z0.z),
                                    fmaf(sres0, ww0.w, gg0.w + z0.w));
        orow[ln + 16] = make_float4(fmaf(sres1, ww1.x, gg1.x + z1.x),
                                    fmaf(sres1, ww1.y, gg1.y + z1.y),
                                    fmaf(sres1, ww1.z, gg1.z + z1.z),
                                    fmaf(sres1, ww1.w, gg1.w + z1.w));
    }
}

extern "C" void kernel_launch(void* const* d_in, const int* in_sizes, int n_in,
                              void* d_out, int out_size, void* d_ws, size_t ws_size,
                              hipStream_t stream) {
    const float* x    = (const float*)d_in[0];
    const int*   ei   = (const int*)  d_in[1];
    const float* attr = (const float*)d_in[2];
    const float* Wl   = (const float*)d_in[3];
    const float* bl   = (const float*)d_in[4];
    const float* Wr   = (const float*)d_in[5];
    const float* br   = (const float*)d_in[6];
    const float* We   = (const float*)d_in[7];
    const float* att  = (const float*)d_in[8];
    const float* bias = (const float*)d_in[9];
    float* out = (float*)d_out;

    const int N = in_sizes[0];       // 50000
    const int E = in_sizes[2];       // 800000
    const int* src = ei;
    const int* dst = ei + E;

    const int nb = (N + BN - 1) / BN;   // 391 buckets of 128 nodes

    // workspace: sorted [nb*CAP]float4 (~16 MB) | gcur [nb]int
    char* w = (char*)d_ws;
    float4* sorted = (float4*)w;
    int*    gcur   = (int*)(w + (size_t)nb * CAP * 16);

    k_init<<<(nb + 255) / 256, 256, 0, stream>>>(gcur, nb);
    k_scatter<<<(E + EPB - 1) / EPB, 256, 0, stream>>>(src, dst, attr, x,
                                                       gcur, sorted, E, nb);
    k_node<<<nb, 512, 0, stream>>>(x, gcur, sorted,
                                   Wl, Wr, We, bl, br, att, bias,
                                   (float4*)out, N);
}

// Round 18
// 74.439 us; speedup vs baseline: 1.3093x; 1.1981x over previous
//
#include <hip/hip_runtime.h>

#define NEG 0.2f

typedef float f4v __attribute__((ext_vector_type(4)));

__device__ __forceinline__ float leaky(float v){ return fmaxf(v, NEG * v); }

// fast -1 fill for head[] (the rocclr fillBuffer path runs at only ~67 GB/s)
__global__ void __launch_bounds__(256) k_fill(int4* __restrict__ p, int n4){
    int t = blockIdx.x * 256 + threadIdx.x;
    if (t < n4) p[t] = make_int4(-1, -1, -1, -1);
}

// ---------------------------------------------------------------------------
// k_edge: 16-lane groups, 16 edges per group. Lane ln owns channels
// ln*8..ln*8+7 (weights in VGPRs) and edge base+ln for all memory traffic:
// coalesced src/dst/attr/x loads, 16 atomicExch in flight, coalesced 32B
// record stores. Record rec[e] = {xs, a, l0, l1, nxt, 0, 0, 0} so the walk
// kernel fetches ONE 64B sector per hop. No nontemporal hints: records stay
// L2/L3-resident for k_walk.
// ---------------------------------------------------------------------------
__global__ void __launch_bounds__(256, 6) k_edge(
        const int* __restrict__ src, const int* __restrict__ dst,
        const float* __restrict__ attr, const float* __restrict__ x,
        const float* __restrict__ Wl, const float* __restrict__ Wr,
        const float* __restrict__ We, const float* __restrict__ bl,
        const float* __restrict__ br, const float* __restrict__ att,
        int* __restrict__ head, float4* __restrict__ rec, int E){
    const int ln = threadIdx.x & 15;               // channel group 0..15
    const float4* Wl4 = (const float4*)Wl;
    const float4* Wr4 = (const float4*)Wr;
    const float4* We4 = (const float4*)We;
    const float4* bl4 = (const float4*)bl;
    const float4* br4 = (const float4*)br;
    const float4* at4 = (const float4*)att;
    const int q = ln * 2;
    float4 wl0 = Wl4[q], wl1 = Wl4[q+1];
    float4 wr0 = Wr4[q], wr1 = Wr4[q+1];
    float4 we0 = We4[q], we1 = We4[q+1];
    float4 b0  = bl4[q], b1  = bl4[q+1];
    float4 c0  = br4[q], c1  = br4[q+1];
    float4 a0  = at4[q], a1  = at4[q+1];
    b0.x += c0.x; b0.y += c0.y; b0.z += c0.z; b0.w += c0.w;
    b1.x += c1.x; b1.y += c1.y; b1.z += c1.z; b1.w += c1.w;

    const int gid  = (blockIdx.x * 256 + threadIdx.x) >> 4;
    const int base = gid * 16;
    if (base >= E) return;

    const int eL = base + ln;
    const bool val = eL < E;
    int   sL = 0, dL = 0;
    float aL = 0.f;
    if (val){ sL = src[eL]; dL = dst[eL]; aL = attr[eL]; }   // coalesced
    float xsL = val ? x[sL] : 0.f;                           // 16 gathers in flight
    float xdL = val ? x[dL] : 0.f;
    int prevL = 0;
    if (val)                                                  // 16 atomics in flight
        prevL = atomicExch(&head[dL * 16 + ln], eL);

    const int cnt = min(16, E - base);
    float l0L = 0.f, l1L = 0.f;
    for (int j = 0; j < cnt; ++j){
        float xs = __shfl(xsL, j, 16);
        float xd = __shfl(xdL, j, 16);
        float a  = __shfl(aL,  j, 16);
        float acc;
        {
            float v0 = fmaf(xs, wl0.x, fmaf(xd, wr0.x, fmaf(a, we0.x, b0.x)));
            float v1 = fmaf(xs, wl0.y, fmaf(xd, wr0.y, fmaf(a, we0.y, b0.y)));
            float v2 = fmaf(xs, wl0.z, fmaf(xd, wr0.z, fmaf(a, we0.z, b0.z)));
            float v3 = fmaf(xs, wl0.w, fmaf(xd, wr0.w, fmaf(a, we0.w, b0.w)));
            acc  = leaky(v0) * a0.x;
            acc  = fmaf(leaky(v1), a0.y, acc);
            acc  = fmaf(leaky(v2), a0.z, acc);
            acc  = fmaf(leaky(v3), a0.w, acc);
            v0 = fmaf(xs, wl1.x, fmaf(xd, wr1.x, fmaf(a, we1.x, b1.x)));
            v1 = fmaf(xs, wl1.y, fmaf(xd, wr1.y, fmaf(a, we1.y, b1.y)));
            v2 = fmaf(xs, wl1.z, fmaf(xd, wr1.z, fmaf(a, we1.z, b1.z)));
            v3 = fmaf(xs, wl1.w, fmaf(xd, wr1.w, fmaf(a, we1.w, b1.w)));
            acc  = fmaf(leaky(v0), a1.x, acc);
            acc  = fmaf(leaky(v1), a1.y, acc);
            acc  = fmaf(leaky(v2), a1.z, acc);
            acc  = fmaf(leaky(v3), a1.w, acc);
        }
        // lanes 0-7 -> head0 sum, lanes 8-15 -> head1 sum; then swap halves
        acc += __shfl_xor(acc, 1);
        acc += __shfl_xor(acc, 2);
        acc += __shfl_xor(acc, 4);
        float other = __shfl_xor(acc, 8);
        if (ln == j){
            l0L = (j < 8) ? acc : other;
            l1L = (j < 8) ? other : acc;
        }
    }
    if (val){
        size_t r = 2 * (size_t)eL;
        rec[r]     = make_float4(xsL, aL, l0L, l1L);
        rec[r + 1] = make_float4(__int_as_float(prevL), 0.f, 0.f, 0.f);
    }
}

// ---------------------------------------------------------------------------
// k_walk: 16 lanes per node; lane ln walks sub-chain ln (avg length 1) with
// exact online softmax (one 64B-sector record per hop); butterfly merge;
// self-loop logit with register weights; fused rank-1 row write.
// head is node-major [N][16] -> coalesced.
// ---------------------------------------------------------------------------
__global__ void __launch_bounds__(256, 6) k_walk(
        const float* __restrict__ x,
        const int* __restrict__ head, const float4* __restrict__ rec,
        const float* __restrict__ Wl, const float* __restrict__ Wr,
        const float* __restrict__ We, const float* __restrict__ bl,
        const float* __restrict__ br, const float* __restrict__ att,
        const float* __restrict__ bias,
        float4* __restrict__ out, int N){
    int t = blockIdx.x * 256 + threadIdx.x;
    int i = t >> 4, ln = t & 15;
    if (i >= N) return;

    const float4* Wl4 = (const float4*)Wl;
    const float4* Wr4 = (const float4*)Wr;
    const float4* We4 = (const float4*)We;
    const float4* bl4 = (const float4*)bl;
    const float4* br4 = (const float4*)br;
    const float4* at4 = (const float4*)att;
    const int q = ln * 2;
    float4 wl0 = Wl4[q], wl1 = Wl4[q+1];
    float4 wr0 = Wr4[q], wr1 = Wr4[q+1];
    float4 we0 = We4[q], we1 = We4[q+1];
    float4 b0  = bl4[q], b1  = bl4[q+1];
    float4 c0  = br4[q], c1  = br4[q+1];
    float4 a0  = at4[q], a1  = at4[q+1];
    wl0.x += wr0.x; wl0.y += wr0.y; wl0.z += wr0.z; wl0.w += wr0.w;
    wl1.x += wr1.x; wl1.y += wr1.y; wl1.z += wr1.z; wl1.w += wr1.w;
    b0.x += c0.x; b0.y += c0.y; b0.z += c0.z; b0.w += c0.w;
    b1.x += c1.x; b1.y += c1.y; b1.z += c1.z; b1.w += c1.w;

    // walk this lane's sub-chain (rec pair = one 64B sector per hop)
    float m0 = -3.4e38f, d0 = 0.f, n0 = 0.f;
    float m1 = -3.4e38f, d1 = 0.f, n1 = 0.f;
    float asum = 0.f;
    int deg = 0;
    for (int e = head[(size_t)i * 16 + ln]; e >= 0; ){
        size_t r = 2 * (size_t)e;
        float4 v = rec[r];                     // (xs, a, l0, l1)
        float4 w = rec[r + 1];                 // (.x = nxt bits)
        e = __float_as_int(w.x);
        ++deg;
        asum += v.y;
        float mn0 = fmaxf(m0, v.z);
        float s0 = __expf(m0 - mn0), p0 = __expf(v.z - mn0);
        d0 = fmaf(d0, s0, p0);
        n0 = fmaf(n0, s0, p0 * v.x);
        m0 = mn0;
        float mn1 = fmaxf(m1, v.w);
        float s1 = __expf(m1 - mn1), p1 = __expf(v.w - mn1);
        d1 = fmaf(d1, s1, p1);
        n1 = fmaf(n1, s1, p1 * v.x);
        m1 = mn1;
    }
    // butterfly merge across the 16 lanes of this node
    #pragma unroll
    for (int off = 1; off < 16; off <<= 1){
        float om0 = __shfl_xor(m0, off), od0 = __shfl_xor(d0, off), on0 = __shfl_xor(n0, off);
        float om1 = __shfl_xor(m1, off), od1 = __shfl_xor(d1, off), on1 = __shfl_xor(n1, off);
        asum += __shfl_xor(asum, off);
        deg  += __shfl_xor(deg, off);
        float mn = fmaxf(m0, om0);
        d0 = d0 * __expf(m0 - mn) + od0 * __expf(om0 - mn);
        n0 = n0 * __expf(m0 - mn) + on0 * __expf(om0 - mn);
        m0 = mn;
        mn = fmaxf(m1, om1);
        d1 = d1 * __expf(m1 - mn) + od1 * __expf(om1 - mn);
        n1 = n1 * __expf(m1 - mn) + on1 * __expf(om1 - mn);
        m1 = mn;
    }
    // self-loop logit, 8 channels per lane
    float xi = x[i];
    float la = asum / (float)max(deg, 1);
    float pl;
    {
        float v0 = fmaf(xi, wl0.x, fmaf(la, we0.x, b0.x));
        float v1 = fmaf(xi, wl0.y, fmaf(la, we0.y, b0.y));
        float v2 = fmaf(xi, wl0.z, fmaf(la, we0.z, b0.z));
        float v3 = fmaf(xi, wl0.w, fmaf(la, we0.w, b0.w));
        pl  = leaky(v0) * a0.x;
        pl  = fmaf(leaky(v1), a0.y, pl);
        pl  = fmaf(leaky(v2), a0.z, pl);
        pl  = fmaf(leaky(v3), a0.w, pl);
        v0 = fmaf(xi, wl1.x, fmaf(la, we1.x, b1.x));
        v1 = fmaf(xi, wl1.y, fmaf(la, we1.y, b1.y));
        v2 = fmaf(xi, wl1.z, fmaf(la, we1.z, b1.z));
        v3 = fmaf(xi, wl1.w, fmaf(la, we1.w, b1.w));
        pl  = fmaf(leaky(v0), a1.x, pl);
        pl  = fmaf(leaky(v1), a1.y, pl);
        pl  = fmaf(leaky(v2), a1.z, pl);
        pl  = fmaf(leaky(v3), a1.w, pl);
    }
    pl += __shfl_xor(pl, 1);
    pl += __shfl_xor(pl, 2);
    pl += __shfl_xor(pl, 4);                 // lanes 0-7: l0, lanes 8-15: l1
    float other = __shfl_xor(pl, 8);
    float l0 = (ln < 8) ? pl : other;
    float l1 = (ln < 8) ? other : pl;
    // fold self-loop into merged softmax state (all lanes redundantly)
    {
        float mn = fmaxf(m0, l0);
        float s = __expf(m0 - mn), p = __expf(l0 - mn);
        d0 = fmaf(d0, s, p);
        n0 = fmaf(n0, s, p * xi);
    }
    {
        float mn = fmaxf(m1, l1);
        float s = __expf(m1 - mn), p = __expf(l1 - mn);
        d1 = fmaf(d1, s, p);
        n1 = fmaf(n1, s, p * xi);
    }
    float sres0 = n0 / d0;
    float sres1 = n1 / d1;

    // fused rank-1 row write: lane ln writes float4 slots ln and ln+16
    float4 w0 = Wl4[ln],      w1 = Wl4[ln + 16];
    float4 g0 = bl4[ln],      g1 = bl4[ln + 16];
    float4 z0 = ((const float4*)bias)[ln], z1 = ((const float4*)bias)[ln + 16];
    float4* orow = out + (size_t)i * 32;
    orow[ln]      = make_float4(fmaf(sres0, w0.x, g0.x + z0.x),
                                fmaf(sres0, w0.y, g0.y + z0.y),
                                fmaf(sres0, w0.z, g0.z + z0.z),
                                fmaf(sres0, w0.w, g0.w + z0.w));
    orow[ln + 16] = make_float4(fmaf(sres1, w1.x, g1.x + z1.x),
                                fmaf(sres1, w1.y, g1.y + z1.y),
                                fmaf(sres1, w1.z, g1.z + z1.z),
                                fmaf(sres1, w1.w, g1.w + z1.w));
}

extern "C" void kernel_launch(void* const* d_in, const int* in_sizes, int n_in,
                              void* d_out, int out_size, void* d_ws, size_t ws_size,
                              hipStream_t stream) {
    const float* x    = (const float*)d_in[0];
    const int*   ei   = (const int*)  d_in[1];
    const float* attr = (const float*)d_in[2];
    const float* Wl   = (const float*)d_in[3];
    const float* bl   = (const float*)d_in[4];
    const float* Wr   = (const float*)d_in[5];
    const float* br   = (const float*)d_in[6];
    const float* We   = (const float*)d_in[7];
    const float* att  = (const float*)d_in[8];
    const float* bias = (const float*)d_in[9];
    float* out = (float*)d_out;

    const int N = in_sizes[0];       // 50000
    const int E = in_sizes[2];       // 800000
    const int* src = ei;
    const int* dst = ei + E;

    // workspace: rec [E][2]float4 (32B/edge) | head [N][16]int   (~28.8 MB)
    char* w = (char*)d_ws;
    float4* rec  = (float4*)w;
    int*    head = (int*)(w + (size_t)E * 32);

    // fast head init to -1 (16N ints = 4N int4s)
    int n4 = 4 * N;
    k_fill<<<(n4 + 255) / 256, 256, 0, stream>>>((int4*)head, n4);

    int egroups = (E + 15) / 16;                    // one 16-edge chunk per group
    int eblocks = (egroups + 15) / 16;              // 16 groups per 256-thr block
    k_edge<<<eblocks, 256, 0, stream>>>(src, dst, attr, x,
                                        Wl, Wr, We, bl, br, att,
                                        head, rec, E);
    k_walk<<<((size_t)16 * N + 255) / 256, 256, 0, stream>>>(x, head, rec,
                                                             Wl, Wr, We, bl, br, att, bias,
                                                             (float4*)out, N);
}